// Round 1
// baseline (2860.400 us; speedup 1.0000x reference)
//
#include <hip/hip_runtime.h>

#define KTAPS 9
#define DIL 6
#define BN_EPS 1e-5f
#define BB 8
#define CIN 256
#define COUT 256
#define NPTS 8192
#define BN 128
#define WROWS 192     // x window rows (points): BN + 2*XOFF
#define WSTRIDE 40    // win row stride in bf16 (40*2B = 80B = 20 banks -> conflict-free b128 reads)
#define XOFF 32       // window row 0 = n0 - XOFF

typedef __attribute__((ext_vector_type(8))) short short8;
typedef __attribute__((ext_vector_type(4))) float f32x4;

__device__ __forceinline__ unsigned short f2bf(float f) {
  union { float f; unsigned u; } v; v.f = f;
  unsigned r = v.u + 0x7fffu + ((v.u >> 16) & 1u);   // RNE
  return (unsigned short)(r >> 16);
}

// ---------------------------------------------------------------- pre: pack W + zero sums
// Wa[chunk][mi][kk]; chunk = ktap*8 + c8; element = W[mi][c8*32+kk][ktap]
__global__ __launch_bounds__(256)
void pre_kernel(const float* __restrict__ W, short* __restrict__ Wa,
                float* __restrict__ sums) {
  int bid = blockIdx.x;
  if (bid < 2304) {
    int idx = bid * 256 + threadIdx.x;
    int kk = idx & 31;
    int mi = (idx >> 5) & 255;
    int chunk = idx >> 13;
    int ktap = chunk >> 3;
    int c = ((chunk & 7) << 5) + kk;
    Wa[idx] = (short)f2bf(W[(size_t)mi * (CIN * KTAPS) + c * KTAPS + ktap]);
  } else {
    if (threadIdx.x < 512) sums[threadIdx.x] = 0.f;
  }
}

// ---------------------------------------------------------------- MFMA conv, post-scale by g
// out = sum_k g[k,n] * (W_k (bf16) @ x (bf16))  -- g applied in f32 after each MFMA.
// B operand: transposed bf16 x-window in LDS (one stage per c8, 1 barrier per c8).
// A operand: registers, loaded directly from L2-resident Wa (no A LDS, no DMA drain).
__global__ __launch_bounds__(256, 2)
void conv_mfma(const float* __restrict__ x, const float* __restrict__ coords,
               const float* __restrict__ rot, const float* __restrict__ dist,
               const short* __restrict__ Wa, const float* __restrict__ bias,
               float* __restrict__ out,
               float* __restrict__ sums1, float* __restrict__ sums2) {
  __shared__ short win[2][WROWS * WSTRIDE];   // 30 KB  [n][c] bf16, dbuf
  __shared__ float g_lds[KTAPS][BN];          // 4.6 KB

  const int tid = threadIdx.x;
  const int b = blockIdx.y;
  const int n0 = blockIdx.x * BN;
  const int wave = tid >> 6;
  const int lane = tid & 63;
  const int col = lane & 15;
  const int quad = lane >> 4;

  // ---- tap weights g[k][n] -> g_lds (one thread per output point)
  if (tid < BN) {
    const float* cb = coords + (size_t)b * 3 * NPTS;
    const float* rb = rot + (size_t)b * 3 * NPTS;
    const float* db = dist + (size_t)b * NPTS;
    int n = n0 + tid;
    float c0x = cb[n], c0y = cb[NPTS + n], c0z = cb[2 * NPTS + n];
    float r0x = rb[n], r0y = rb[NPTS + n], r0z = rb[2 * NPTS + n];
    float d0 = db[n];
    float r0n = r0x * r0x + r0y * r0y + r0z * r0z;
#pragma unroll
    for (int k = 0; k < KTAPS; ++k) {
      int j = n + (k - KTAPS / 2) * DIL;
      float gv = 0.f;
      if (j >= 0 && j < NPTS) {
        float dcx = c0x - cb[j], dcy = c0y - cb[NPTS + j], dcz = c0z - cb[2 * NPTS + j];
        float dc = dcx * dcx + dcy * dcy + dcz * dcz;
        float dd = d0 - db[j];
        dd *= dd;
        float gauss = expf(-(dc + dd) * 0.5f);
        float rjx = rb[j], rjy = rb[NPTS + j], rjz = rb[2 * NPTS + j];
        float num = r0x * rjx + r0y * rjy + r0z * rjz;
        float den = sqrtf(r0n * (rjx * rjx + rjy * rjy + rjz * rjz)) + 1e-8f;
        gv = gauss * fabsf(num / den);
      }
      g_lds[k][tid] = gv;
    }
  }

  const float* xb = x + (size_t)b * CIN * NPTS;
  const int xchl = tid >> 3;        // staged channel 0..31
  const int xc0 = (tid & 7) * 4;    // staged col base
  const int arow0 = (wave * 64 + col) * 32 + quad * 8;  // short offset inside a Wa chunk

  float4 xr[6];                     // global->reg stage for next c8

#define STAGE_LOAD(C8)                                                  \
  {                                                                     \
    const float* xrow_ = xb + (size_t)((C8) * 32 + xchl) * NPTS;        \
    _Pragma("unroll")                                                   \
    for (int q = 0; q < 6; ++q) {                                       \
      int cw_ = xc0 + q * 32;                                           \
      int jg_ = n0 - XOFF + cw_;                                        \
      float4 v_;                                                        \
      if (jg_ >= 0 && jg_ + 3 < NPTS) {                                 \
        v_ = *(const float4*)&xrow_[jg_];                               \
      } else {                                                          \
        float* e_ = (float*)&v_;                                        \
        _Pragma("unroll")                                               \
        for (int u = 0; u < 4; ++u) {                                   \
          int jj_ = jg_ + u;                                            \
          e_[u] = (jj_ >= 0 && jj_ < NPTS) ? xrow_[jj_] : 0.f;          \
        }                                                               \
      }                                                                 \
      xr[q] = v_;                                                       \
    }                                                                   \
  }

#define STAGE_WRITE(BUF)                                                \
  {                                                                     \
    _Pragma("unroll")                                                   \
    for (int q = 0; q < 6; ++q) {                                       \
      int cw_ = xc0 + q * 32;                                           \
      _Pragma("unroll")                                                 \
      for (int u = 0; u < 4; ++u)                                       \
        win[BUF][(cw_ + u) * WSTRIDE + xchl] =                          \
            (short)f2bf(((const float*)&xr[q])[u]);                     \
    }                                                                   \
  }

  short8 afA[4], afB[4];
#define LOADAF(AF, CHUNK)                                               \
  {                                                                     \
    const short* p_ = Wa + (size_t)(CHUNK) * 8192 + arow0;              \
    _Pragma("unroll")                                                   \
    for (int m = 0; m < 4; ++m) AF[m] = *(const short8*)(p_ + m * 512); \
  }

  f32x4 acc[4][8];
#pragma unroll
  for (int m = 0; m < 4; ++m)
#pragma unroll
    for (int j = 0; j < 8; ++j) acc[m][j] = (f32x4)0.f;

  // prologue: stage window for c8=0, preload A for (k=0,c8=0)
  STAGE_LOAD(0);
  STAGE_WRITE(0);
  LOADAF(afA, 0);
  __syncthreads();   // win[0] + g_lds published

  const f32x4 zero4 = (f32x4)0.f;

#define TAP_BODY(K, AF)                                                     \
  {                                                                         \
    float gk[8];                                                            \
    _Pragma("unroll")                                                       \
    for (int j = 0; j < 8; ++j) gk[j] = g_lds[K][j * 16 + col];             \
    const int wb_ = XOFF + ((K)-KTAPS / 2) * DIL;                           \
    _Pragma("unroll")                                                       \
    for (int j = 0; j < 8; ++j) {                                           \
      short8 bfv = *(const short8*)&wcur[(wb_ + j * 16 + col) * WSTRIDE + quad * 8]; \
      _Pragma("unroll")                                                     \
      for (int m = 0; m < 4; ++m) {                                         \
        f32x4 t_ = __builtin_amdgcn_mfma_f32_16x16x32_bf16(AF[m], bfv, zero4, 0, 0, 0); \
        float g_ = gk[j];                                                   \
        acc[m][j][0] += g_ * t_[0];                                         \
        acc[m][j][1] += g_ * t_[1];                                         \
        acc[m][j][2] += g_ * t_[2];                                         \
        acc[m][j][3] += g_ * t_[3];                                         \
      }                                                                     \
    }                                                                       \
  }

  int cur = 0;
  for (int c8 = 0; c8 < 8; ++c8) {
    if (c8 < 7) STAGE_LOAD(c8 + 1);   // HBM latency hides under the 9-tap MFMA stretch
    const short* wcur = &win[cur][0];

    // 9 taps, barrier-free; A double-buffered one tap ahead from L2-resident Wa
    LOADAF(afB, 8 + c8);   TAP_BODY(0, afA);
    LOADAF(afA, 16 + c8);  TAP_BODY(1, afB);
    LOADAF(afB, 24 + c8);  TAP_BODY(2, afA);
    LOADAF(afA, 32 + c8);  TAP_BODY(3, afB);
    LOADAF(afB, 40 + c8);  TAP_BODY(4, afA);
    LOADAF(afA, 48 + c8);  TAP_BODY(5, afB);
    LOADAF(afB, 56 + c8);  TAP_BODY(6, afA);
    LOADAF(afA, 64 + c8);  TAP_BODY(7, afB);
    TAP_BODY(8, afA);

    if (c8 < 7) {
      LOADAF(afA, c8 + 1);           // A for next c8, k=0
      STAGE_WRITE(cur ^ 1);          // write other buffer: safe without a pre-barrier
      __syncthreads();               // publish win[cur^1]  (1 barrier per c8)
      cur ^= 1;
    }
  }

  // ---- epilogue: bias, BN partial sums, store (unchanged, previously verified)
  const int obase = wave * 64;
  float* outp = out + (size_t)b * COUT * NPTS + n0;
#pragma unroll
  for (int m = 0; m < 4; ++m) {
    const int o0 = obase + m * 16 + quad * 4;
    const float4 bv = *(const float4*)&bias[o0];
#pragma unroll
    for (int j = 0; j < 8; ++j) {
      acc[m][j][0] += bv.x; acc[m][j][1] += bv.y;
      acc[m][j][2] += bv.z; acc[m][j][3] += bv.w;
    }
#pragma unroll
    for (int r = 0; r < 4; ++r) {
      float s1 = 0.f, s2 = 0.f;
#pragma unroll
      for (int j = 0; j < 8; ++j) {
        float v = acc[m][j][r];
        s1 += v; s2 += v * v;
      }
      s1 += __shfl_xor(s1, 1); s2 += __shfl_xor(s2, 1);
      s1 += __shfl_xor(s1, 2); s2 += __shfl_xor(s2, 2);
      s1 += __shfl_xor(s1, 4); s2 += __shfl_xor(s2, 4);
      s1 += __shfl_xor(s1, 8); s2 += __shfl_xor(s2, 8);
      if (col == 0) {
        atomicAdd(&sums1[o0 + r], s1);
        atomicAdd(&sums2[o0 + r], s2);
      }
#pragma unroll
      for (int j = 0; j < 8; ++j)
        outp[(size_t)(o0 + r) * NPTS + j * 16 + col] = acc[m][j][r];
    }
  }
}

// ---------------------------------------------------------------- BN + ReLU
__global__ __launch_bounds__(256)
void bn_apply(float* __restrict__ out, const float* __restrict__ sums1,
              const float* __restrict__ sums2, const float* __restrict__ gamma,
              const float* __restrict__ beta) {
  int bo = blockIdx.x;
  int o = bo & (COUT - 1);
  const float inv = 1.f / (float)(BB * NPTS);
  float mean = sums1[o] * inv;
  float var = sums2[o] * inv - mean * mean;
  float scale = gamma[o] * rsqrtf(var + BN_EPS);
  float shift = beta[o] - mean * scale;
  float4* p = (float4*)(out + (size_t)bo * NPTS);
  for (int i = threadIdx.x; i < NPTS / 4; i += blockDim.x) {
    float4 v = p[i];
    v.x = fmaxf(fmaf(v.x, scale, shift), 0.f);
    v.y = fmaxf(fmaf(v.y, scale, shift), 0.f);
    v.z = fmaxf(fmaf(v.z, scale, shift), 0.f);
    v.w = fmaxf(fmaf(v.w, scale, shift), 0.f);
    p[i] = v;
  }
}

// ---------------------------------------------------------------- launch
extern "C" void kernel_launch(void* const* d_in, const int* in_sizes, int n_in,
                              void* d_out, int out_size, void* d_ws, size_t ws_size,
                              hipStream_t stream) {
  const float* x      = (const float*)d_in[0];
  const float* coords = (const float*)d_in[1];
  const float* rot    = (const float*)d_in[2];
  const float* dist   = (const float*)d_in[3];
  const float* W      = (const float*)d_in[4];
  const float* bias   = (const float*)d_in[5];
  const float* gamma  = (const float*)d_in[6];
  const float* beta   = (const float*)d_in[7];
  float* out = (float*)d_out;

  float* ws    = (float*)d_ws;
  float* sums1 = ws;                    // 256
  float* sums2 = ws + 256;              // 256
  short* Wa    = (short*)(ws + 512);    // 72*8192 bf16

  pre_kernel<<<2305, 256, 0, stream>>>(W, Wa, sums1);
  conv_mfma<<<dim3(NPTS / BN, BB), 256, 0, stream>>>(x, coords, rot, dist, Wa, bias, out, sums1, sums2);
  bn_apply<<<BB * COUT, 256, 0, stream>>>(out, sums1, sums2, gamma, beta);
}

// Round 2
// 324.319 us; speedup vs baseline: 8.8197x; 8.8197x over previous
//
#include <hip/hip_runtime.h>

#define KTAPS 9
#define DIL 6
#define BN_EPS 1e-5f
#define BB 8
#define CIN 256
#define COUT 256
#define NPTS 8192
#define BN 64
#define BSTRIDE 40   // B_all row stride in shorts (80 B = 20 banks -> uniform b128 access)

typedef __attribute__((ext_vector_type(8))) short short8;
typedef __attribute__((ext_vector_type(4))) float f32x4;

__device__ __forceinline__ unsigned short f2bf(float f) {
  union { float f; unsigned u; } v; v.f = f;
  unsigned r = v.u + 0x7fffu + ((v.u >> 16) & 1u);   // RNE
  return (unsigned short)(r >> 16);
}

// ---------------------------------------------------------------- pre: pack W + zero sums
// Wa[chunk][mi][kk]; chunk = ktap*8 + c8; element = W[mi][c8*32+kk][ktap]
__global__ __launch_bounds__(256)
void pre_kernel(const float* __restrict__ W, short* __restrict__ Wa,
                float* __restrict__ sums) {
  int bid = blockIdx.x;
  if (bid < 2304) {
    int idx = bid * 256 + threadIdx.x;
    int kk = idx & 31;
    int mi = (idx >> 5) & 255;
    int chunk = idx >> 13;
    int ktap = chunk >> 3;
    int c = ((chunk & 7) << 5) + kk;
    Wa[idx] = (short)f2bf(W[(size_t)mi * (CIN * KTAPS) + c * KTAPS + ktap]);
  } else {
    if (threadIdx.x < 512) sums[threadIdx.x] = 0.f;
  }
}

// ---------------------------------------------------------------- MFMA conv
// Per c8 (channel octet): build B for ALL 9 taps into LDS (g baked, f2bf(x_f32*g)),
// one barrier, then 9 taps x 16 MFMA per wave with in-place AGPR accumulate,
// one barrier. 2 barriers/c8 = 17 total (vs 88 before).
// A operand: register double-buffer loaded straight from L2-resident Wa.
__global__ __launch_bounds__(256, 2)
void conv_mfma(const float* __restrict__ x, const float* __restrict__ coords,
               const float* __restrict__ rot, const float* __restrict__ dist,
               const short* __restrict__ Wa, const float* __restrict__ bias,
               float* __restrict__ out,
               float* __restrict__ sums1, float* __restrict__ sums2) {
  __shared__ short B_all[KTAPS][BN][BSTRIDE];  // 45 KB, single-buffered
  __shared__ float g_lds[KTAPS][BN];           // 2.3 KB

  const int tid = threadIdx.x;
  const int b = blockIdx.y;
  const int n0 = blockIdx.x * BN;
  const int wave = tid >> 6;
  const int lane = tid & 63;
  const int col = lane & 15;
  const int quad = lane >> 4;
  const int nb = tid & 63;          // build: point index within tile
  const int q8 = (tid >> 6) * 8;    // build: channel granule base (0,8,16,24)

  // ---- tap weights g[k][nb] -> g_lds; wave w computes taps {w, w+4, w+8}
  {
    const float* cb = coords + (size_t)b * 3 * NPTS;
    const float* rb = rot + (size_t)b * 3 * NPTS;
    const float* db = dist + (size_t)b * NPTS;
    int n = n0 + nb;
    float c0x = cb[n], c0y = cb[NPTS + n], c0z = cb[2 * NPTS + n];
    float r0x = rb[n], r0y = rb[NPTS + n], r0z = rb[2 * NPTS + n];
    float d0 = db[n];
    float r0n = r0x * r0x + r0y * r0y + r0z * r0z;
    for (int k = wave; k < KTAPS; k += 4) {
      int j = n + (k - KTAPS / 2) * DIL;
      float gv = 0.f;
      if (j >= 0 && j < NPTS) {
        float dcx = c0x - cb[j], dcy = c0y - cb[NPTS + j], dcz = c0z - cb[2 * NPTS + j];
        float dc = dcx * dcx + dcy * dcy + dcz * dcz;
        float dd = d0 - db[j];
        dd *= dd;
        float gauss = expf(-(dc + dd) * 0.5f);
        float rjx = rb[j], rjy = rb[NPTS + j], rjz = rb[2 * NPTS + j];
        float num = r0x * rjx + r0y * rjy + r0z * rjz;
        float den = sqrtf(r0n * (rjx * rjx + rjy * rjy + rjz * rjz)) + 1e-8f;
        gv = gauss * fabsf(num / den);
      }
      g_lds[k][nb] = gv;
    }
  }
  __syncthreads();   // g_lds published

  const float* xb = x + (size_t)b * CIN * NPTS;
  const int arow0 = (wave * 64 + col) * 32 + quad * 8;  // short offset inside a Wa chunk

  short8 afA[4], afB[4];
#define LOADAF(AF, CHUNK)                                               \
  {                                                                     \
    const short* p_ = Wa + (size_t)(CHUNK) * 8192 + arow0;              \
    _Pragma("unroll")                                                   \
    for (int m = 0; m < 4; ++m) AF[m] = *(const short8*)(p_ + m * 512); \
  }

#define TAPM(K, AF)                                                     \
  {                                                                     \
    _Pragma("unroll")                                                   \
    for (int j = 0; j < 4; ++j) {                                       \
      short8 bfv = *(const short8*)&B_all[K][j * 16 + col][quad * 8];   \
      _Pragma("unroll")                                                 \
      for (int m = 0; m < 4; ++m)                                       \
        acc[m][j] = __builtin_amdgcn_mfma_f32_16x16x32_bf16(AF[m], bfv, acc[m][j], 0, 0, 0); \
    }                                                                   \
  }

  f32x4 acc[4][4];
#pragma unroll
  for (int m = 0; m < 4; ++m)
#pragma unroll
    for (int j = 0; j < 4; ++j) acc[m][j] = (f32x4)0.f;

  for (int c8 = 0; c8 < 8; ++c8) {
    // ---- A for tap 0 of this c8 (L2 latency hides under the build)
    LOADAF(afA, c8);

    // ---- build B for all 9 taps: thread owns (nb, channel granule q8), loops taps.
    //      x reads: per-lane consecutive n -> coalesced; 9x tap overlap served by L1.
    {
      const float* xc = xb + (size_t)(c8 * 32 + q8) * NPTS;
#pragma unroll 1
      for (int k = 0; k < KTAPS; ++k) {
        int jpos = n0 + nb + (k - KTAPS / 2) * DIL;
        int jc = jpos < 0 ? 0 : (jpos >= NPTS ? NPTS - 1 : jpos);
        float gk = g_lds[k][nb];   // 0 when jpos OOB -> B = 0 (matches zero-padding)
        short8 p;
#pragma unroll
        for (int cc = 0; cc < 8; ++cc)
          p[cc] = (short)f2bf(xc[(size_t)cc * NPTS + jc] * gk);
        *(short8*)&B_all[k][nb][q8] = p;
      }
    }
    __syncthreads();   // B_all ready

    // ---- 9 taps, barrier-free; A double-buffered one tap ahead from L2
    LOADAF(afB, 8 + c8);   TAPM(0, afA);
    LOADAF(afA, 16 + c8);  TAPM(1, afB);
    LOADAF(afB, 24 + c8);  TAPM(2, afA);
    LOADAF(afA, 32 + c8);  TAPM(3, afB);
    LOADAF(afB, 40 + c8);  TAPM(4, afA);
    LOADAF(afA, 48 + c8);  TAPM(5, afB);
    LOADAF(afB, 56 + c8);  TAPM(6, afA);
    LOADAF(afA, 64 + c8);  TAPM(7, afB);
    TAPM(8, afA);
    __syncthreads();   // B_all consumed; next c8 may overwrite
  }

  // ---- epilogue: bias, BN partial sums, store
  const int obase = wave * 64;
  float* outp = out + (size_t)b * COUT * NPTS + n0;
#pragma unroll
  for (int m = 0; m < 4; ++m) {
    const int o0 = obase + m * 16 + quad * 4;
    const float4 bv = *(const float4*)&bias[o0];
#pragma unroll
    for (int j = 0; j < 4; ++j) {
      acc[m][j][0] += bv.x; acc[m][j][1] += bv.y;
      acc[m][j][2] += bv.z; acc[m][j][3] += bv.w;
    }
#pragma unroll
    for (int r = 0; r < 4; ++r) {
      float s1 = 0.f, s2 = 0.f;
#pragma unroll
      for (int j = 0; j < 4; ++j) {
        float v = acc[m][j][r];
        s1 += v; s2 += v * v;
      }
      s1 += __shfl_xor(s1, 1); s2 += __shfl_xor(s2, 1);
      s1 += __shfl_xor(s1, 2); s2 += __shfl_xor(s2, 2);
      s1 += __shfl_xor(s1, 4); s2 += __shfl_xor(s2, 4);
      s1 += __shfl_xor(s1, 8); s2 += __shfl_xor(s2, 8);
      if (col == 0) {
        atomicAdd(&sums1[o0 + r], s1);
        atomicAdd(&sums2[o0 + r], s2);
      }
#pragma unroll
      for (int j = 0; j < 4; ++j)
        outp[(size_t)(o0 + r) * NPTS + j * 16 + col] = acc[m][j][r];
    }
  }
}

// ---------------------------------------------------------------- BN + ReLU
__global__ __launch_bounds__(256)
void bn_apply(float* __restrict__ out, const float* __restrict__ sums1,
              const float* __restrict__ sums2, const float* __restrict__ gamma,
              const float* __restrict__ beta) {
  int bo = blockIdx.x;
  int o = bo & (COUT - 1);
  const float inv = 1.f / (float)(BB * NPTS);
  float mean = sums1[o] * inv;
  float var = sums2[o] * inv - mean * mean;
  float scale = gamma[o] * rsqrtf(var + BN_EPS);
  float shift = beta[o] - mean * scale;
  float4* p = (float4*)(out + (size_t)bo * NPTS);
  for (int i = threadIdx.x; i < NPTS / 4; i += blockDim.x) {
    float4 v = p[i];
    v.x = fmaxf(fmaf(v.x, scale, shift), 0.f);
    v.y = fmaxf(fmaf(v.y, scale, shift), 0.f);
    v.z = fmaxf(fmaf(v.z, scale, shift), 0.f);
    v.w = fmaxf(fmaf(v.w, scale, shift), 0.f);
    p[i] = v;
  }
}

// ---------------------------------------------------------------- launch
extern "C" void kernel_launch(void* const* d_in, const int* in_sizes, int n_in,
                              void* d_out, int out_size, void* d_ws, size_t ws_size,
                              hipStream_t stream) {
  const float* x      = (const float*)d_in[0];
  const float* coords = (const float*)d_in[1];
  const float* rot    = (const float*)d_in[2];
  const float* dist   = (const float*)d_in[3];
  const float* W      = (const float*)d_in[4];
  const float* bias   = (const float*)d_in[5];
  const float* gamma  = (const float*)d_in[6];
  const float* beta   = (const float*)d_in[7];
  float* out = (float*)d_out;

  float* ws    = (float*)d_ws;
  float* sums1 = ws;                    // 256
  float* sums2 = ws + 256;              // 256
  short* Wa    = (short*)(ws + 512);    // 72*8192 bf16

  pre_kernel<<<2305, 256, 0, stream>>>(W, Wa, sums1);
  conv_mfma<<<dim3(NPTS / BN, BB), 256, 0, stream>>>(x, coords, rot, dist, Wa, bias, out, sums1, sums2);
  bn_apply<<<BB * COUT, 256, 0, stream>>>(out, sums1, sums2, gamma, beta);
}